// Round 1
// baseline (179.742 us; speedup 1.0000x reference)
//
#include <hip/hip_runtime.h>
#include <cstdint>
#include <cstddef>

constexpr int kN = 2048;   // layer size (power of 2 -> cheap mod)
constexpr int kB = 4096;   // batch
constexpr int kR = 4;      // displacement rank

typedef __attribute__((ext_vector_type(4))) float f32x4;
typedef __attribute__((ext_vector_type(8))) short short8;
typedef __attribute__((ext_vector_type(8))) unsigned short ushort8;

__device__ __forceinline__ unsigned short f2bf(float f) {
  unsigned u = __float_as_uint(f);
  u += 0x7FFFu + ((u >> 16) & 1u);   // round-to-nearest-even
  return (unsigned short)(u >> 16);
}

__device__ __forceinline__ void gload_lds16(const void* g, void* l) {
  __builtin_amdgcn_global_load_lds(
      (const __attribute__((address_space(1))) void*)g,
      (__attribute__((address_space(3))) void*)l, 16, 0, 0);
}

// ---------------- kernel 1: x (f32) -> xb (bf16) ----------------
__global__ void cast_x_kernel(const float* __restrict__ x,
                              unsigned short* __restrict__ xb) {
  const int t = blockIdx.x * blockDim.x + threadIdx.x;   // 1M threads, 8 elem each
  const float4* xv = (const float4*)x;
  float4 a = xv[t * 2];
  float4 b = xv[t * 2 + 1];
  ushort8 o;
  o[0] = f2bf(a.x); o[1] = f2bf(a.y); o[2] = f2bf(a.z); o[3] = f2bf(a.w);
  o[4] = f2bf(b.x); o[5] = f2bf(b.y); o[6] = f2bf(b.z); o[7] = f2bf(b.w);
  *(ushort8*)(xb + (size_t)t * 8) = o;
}

// ---------------- kernel 2: per-diagonal prefix scan ----------------
// Dp[d][j] = 2 * sum_{v<=j} q_d[v] - sum_v q_d[v],  q_d[v] = sum_t G[t][(v+d)%n]*H[t][v]
__global__ void build_D_kernel(const float* __restrict__ G,
                               const float* __restrict__ H,
                               unsigned short* __restrict__ Dp) {
  const int d = blockIdx.x;
  const int tid = threadIdx.x;          // 256 threads, 8 v each
  const int lane = tid & 63, wave = tid >> 6;
  const int v0 = tid * 8;

  float loc[8];
  float run = 0.f;
#pragma unroll
  for (int jj = 0; jj < 8; ++jj) {
    const int v = v0 + jj;
    float q = 0.f;
#pragma unroll
    for (int t = 0; t < kR; ++t)
      q += G[t * kN + ((v + d) & (kN - 1))] * H[t * kN + v];
    run += q;
    loc[jj] = run;                      // inclusive within thread
  }

  // wave-level inclusive scan of per-thread sums
  float incl = run;
#pragma unroll
  for (int off = 1; off < 64; off <<= 1) {
    float tv = __shfl_up(incl, off, 64);
    if (lane >= off) incl += tv;
  }
  __shared__ float wsum[4];
  if (lane == 63) wsum[wave] = incl;
  __syncthreads();
  float woff = 0.f, total = 0.f;
#pragma unroll
  for (int w = 0; w < 4; ++w) {
    const float s = wsum[w];
    total += s;
    if (w < wave) woff += s;
  }
  const float exc = woff + incl - run;  // exclusive prefix for this thread

  ushort8 o;
#pragma unroll
  for (int jj = 0; jj < 8; ++jj)
    o[jj] = f2bf(2.f * (exc + loc[jj]) - total);
  *(ushort8*)(Dp + (size_t)d * kN + v0) = o;
}

// ---------------- kernel 3: diagonal -> row-major transpose ----------------
// Mb[i][j] = Dp[(i-j)&2047][j], tiled 64x64 through LDS for coalescing
__global__ void build_M_kernel(const unsigned short* __restrict__ Dp,
                               unsigned short* __restrict__ Mb) {
  __shared__ unsigned short lds[128][64];
  const int tid = threadIdx.x;
  const int i0 = blockIdx.y * 64, j0 = blockIdx.x * 64;
  const int delta0 = (i0 - j0 - 63) & (kN - 1);
#pragma unroll
  for (int it = 0; it < 32; ++it) {
    const int lin = it * 256 + tid;     // 0..8191
    const int dd = lin >> 6, jj = lin & 63;
    lds[dd][jj] = Dp[(size_t)((delta0 + dd) & (kN - 1)) * kN + j0 + jj];
  }
  __syncthreads();
#pragma unroll
  for (int it = 0; it < 16; ++it) {
    const int lin = it * 256 + tid;     // 0..4095
    const int ii = lin >> 6, jj = lin & 63;
    Mb[(size_t)(i0 + ii) * kN + j0 + jj] = lds[ii - jj + 63][jj];
  }
}

// ---------------- kernel 4: out = x @ M^T  (bf16 MFMA GEMM, m97 structure) ----------------
// A = xb [4096][2048], Bt = Mb [2048][2048] (row i = output col, contiguous in k)
__global__ __launch_bounds__(256) void gemm_kernel(
    const unsigned short* __restrict__ A,
    const unsigned short* __restrict__ Bt,
    float* __restrict__ C) {
  __shared__ unsigned short As[128][32];   // 8 KB
  __shared__ unsigned short Bs[128][32];   // 8 KB

  const int tid = threadIdx.x;
  const int lane = tid & 63, wave = tid >> 6;
  const int wr = wave >> 1, wc = wave & 1;          // 2x2 waves, 64x64 each
  const int r16 = lane & 15, kg = lane >> 4;
  const int row0 = blockIdx.y * 128;                 // batch dim
  const int col0 = blockIdx.x * 128;                 // output-feature dim

  f32x4 acc[4][4] = {};

  const int srow = tid >> 2;            // 0..63 within 64-row chunk
  const int scol = (tid & 3) * 8;       // 0..31, 8-elem aligned

  for (int k0 = 0; k0 < kN; k0 += 32) {
    __syncthreads();                    // previous tile fully consumed
#pragma unroll
    for (int s = 0; s < 2; ++s) {
      gload_lds16(A + (size_t)(row0 + s * 64 + srow) * kN + k0 + scol,
                  (char*)As + s * 4096 + wave * 1024);
      gload_lds16(Bt + (size_t)(col0 + s * 64 + srow) * kN + k0 + scol,
                  (char*)Bs + s * 4096 + wave * 1024);
    }
    __syncthreads();                    // staging complete (vmcnt drained)

    short8 af[4], bf[4];
#pragma unroll
    for (int mt = 0; mt < 4; ++mt)
      af[mt] = *(const short8*)&As[wr * 64 + mt * 16 + r16][kg * 8];
#pragma unroll
    for (int nt = 0; nt < 4; ++nt)
      bf[nt] = *(const short8*)&Bs[wc * 64 + nt * 16 + r16][kg * 8];
#pragma unroll
    for (int mt = 0; mt < 4; ++mt)
#pragma unroll
      for (int nt = 0; nt < 4; ++nt)
        acc[mt][nt] = __builtin_amdgcn_mfma_f32_16x16x32_bf16(
            af[mt], bf[nt], acc[mt][nt], 0, 0, 0);
  }

  // epilogue: D row = (lane>>4)*4 + reg, col = lane&15 (verified layout)
#pragma unroll
  for (int mt = 0; mt < 4; ++mt)
#pragma unroll
    for (int nt = 0; nt < 4; ++nt) {
      const int r = row0 + wr * 64 + mt * 16 + kg * 4;
      const int c = col0 + wc * 64 + nt * 16 + r16;
#pragma unroll
      for (int j = 0; j < 4; ++j)
        C[(size_t)(r + j) * kN + c] = acc[mt][nt][j];
    }
}

extern "C" void kernel_launch(void* const* d_in, const int* in_sizes, int n_in,
                              void* d_out, int out_size, void* d_ws, size_t ws_size,
                              hipStream_t stream) {
  const float* x = (const float*)d_in[0];
  const float* G = (const float*)d_in[1];
  const float* H = (const float*)d_in[2];
  float* out = (float*)d_out;

  char* ws = (char*)d_ws;
  unsigned short* Mb = (unsigned short*)ws;                      // 8 MB  bf16 M[i][j]
  unsigned short* xb = (unsigned short*)(ws + (8u << 20));       // 16 MB bf16 x
  unsigned short* Dp = (unsigned short*)(ws + (24u << 20));      // 8 MB  bf16 diag-major
  // total workspace: 32 MB

  cast_x_kernel<<<dim3((kB * kN) / (256 * 8)), dim3(256), 0, stream>>>(x, xb);
  build_D_kernel<<<dim3(kN), dim3(256), 0, stream>>>(G, H, Dp);
  build_M_kernel<<<dim3(kN / 64, kN / 64), dim3(256), 0, stream>>>(Dp, Mb);
  gemm_kernel<<<dim3(kN / 128, kB / 128), dim3(256), 0, stream>>>(xb, Mb, out);
}

// Round 2
// 175.498 us; speedup vs baseline: 1.0242x; 1.0242x over previous
//
#include <hip/hip_runtime.h>
#include <cstdint>
#include <cstddef>

constexpr int kN = 2048;   // layer size (power of 2 -> cheap mod)
constexpr int kB = 4096;   // batch
constexpr int kR = 4;      // displacement rank

typedef __attribute__((ext_vector_type(4))) float f32x4;
typedef __attribute__((ext_vector_type(8))) short short8;
typedef __attribute__((ext_vector_type(8))) unsigned short ushort8;

__device__ __forceinline__ unsigned short f2bf(float f) {
  unsigned u = __float_as_uint(f);
  u += 0x7FFFu + ((u >> 16) & 1u);   // round-to-nearest-even
  return (unsigned short)(u >> 16);
}

__device__ __forceinline__ void gload_lds16(const void* g, void* l) {
  __builtin_amdgcn_global_load_lds(
      (const __attribute__((address_space(1))) void*)g,
      (__attribute__((address_space(3))) void*)l, 16, 0, 0);
}

// ---------------- kernel 1 (fused): cast x->bf16  +  per-diagonal prefix scan ----------------
// blocks [0, 4096)   : xb = bf16(x), 8 elem/thread
// blocks [4096, 6144): Dp[d][j] = 2*sum_{v<=j} q_d[v] - sum_v q_d[v],
//                      q_d[v] = sum_t G[t][(v+d)%n]*H[t][v]
__global__ void prep_kernel(const float* __restrict__ x,
                            const float* __restrict__ G,
                            const float* __restrict__ H,
                            unsigned short* __restrict__ xb,
                            unsigned short* __restrict__ Dp) {
  __shared__ float wsum[4];
  const int tid = threadIdx.x;

  if (blockIdx.x < (kB * kN) / (256 * 8)) {
    // ---- cast part ----
    const int t = blockIdx.x * 256 + tid;
    const float4* xv = (const float4*)x;
    float4 a = xv[t * 2];
    float4 b = xv[t * 2 + 1];
    ushort8 o;
    o[0] = f2bf(a.x); o[1] = f2bf(a.y); o[2] = f2bf(a.z); o[3] = f2bf(a.w);
    o[4] = f2bf(b.x); o[5] = f2bf(b.y); o[6] = f2bf(b.z); o[7] = f2bf(b.w);
    *(ushort8*)(xb + (size_t)t * 8) = o;
    return;
  }

  // ---- diagonal-scan part ----
  const int d = blockIdx.x - (kB * kN) / (256 * 8);
  const int lane = tid & 63, wave = tid >> 6;
  const int v0 = tid * 8;

  float loc[8];
  float run = 0.f;
#pragma unroll
  for (int jj = 0; jj < 8; ++jj) {
    const int v = v0 + jj;
    float q = 0.f;
#pragma unroll
    for (int t = 0; t < kR; ++t)
      q += G[t * kN + ((v + d) & (kN - 1))] * H[t * kN + v];
    run += q;
    loc[jj] = run;                      // inclusive within thread
  }

  float incl = run;
#pragma unroll
  for (int off = 1; off < 64; off <<= 1) {
    float tv = __shfl_up(incl, off, 64);
    if (lane >= off) incl += tv;
  }
  if (lane == 63) wsum[wave] = incl;
  __syncthreads();
  float woff = 0.f, total = 0.f;
#pragma unroll
  for (int w = 0; w < 4; ++w) {
    const float s = wsum[w];
    total += s;
    if (w < wave) woff += s;
  }
  const float exc = woff + incl - run;  // exclusive prefix for this thread

  ushort8 o;
#pragma unroll
  for (int jj = 0; jj < 8; ++jj)
    o[jj] = f2bf(2.f * (exc + loc[jj]) - total);
  *(ushort8*)(Dp + (size_t)d * kN + v0) = o;
}

// ---------------- kernel 2: diagonal -> row-major transpose ----------------
// Mb[i][j] = Dp[(i-j)&2047][j], tiled 64x64 through LDS for coalescing
__global__ void build_M_kernel(const unsigned short* __restrict__ Dp,
                               unsigned short* __restrict__ Mb) {
  __shared__ unsigned short lds[128][64];
  const int tid = threadIdx.x;
  const int i0 = blockIdx.y * 64, j0 = blockIdx.x * 64;
  const int delta0 = (i0 - j0 - 63) & (kN - 1);
#pragma unroll
  for (int it = 0; it < 32; ++it) {
    const int lin = it * 256 + tid;     // 0..8191
    const int dd = lin >> 6, jj = lin & 63;
    lds[dd][jj] = Dp[(size_t)((delta0 + dd) & (kN - 1)) * kN + j0 + jj];
  }
  __syncthreads();
#pragma unroll
  for (int it = 0; it < 16; ++it) {
    const int lin = it * 256 + tid;     // 0..4095
    const int ii = lin >> 6, jj = lin & 63;
    Mb[(size_t)(i0 + ii) * kN + j0 + jj] = lds[ii - jj + 63][jj];
  }
}

// ---------------- kernel 3: out = x @ M^T  (bf16 MFMA GEMM) ----------------
// BM=128 x BN=64, BK=32. Grid 32x32 = 1024 blocks = 4 blocks/CU (occupancy fix
// vs 128x128's 512 blocks = 2/CU which measured MfmaUtil 21.8%, Occ 18.8%).
// A = xb [4096][2048], Bt = Mb [2048][2048] (row i = output col, contig in k)
__global__ __launch_bounds__(256) void gemm_kernel(
    const unsigned short* __restrict__ A,
    const unsigned short* __restrict__ Bt,
    float* __restrict__ C) {
  __shared__ unsigned short As[128][32];   // 8 KB
  __shared__ unsigned short Bs[64][32];    // 4 KB

  const int tid = threadIdx.x;
  const int lane = tid & 63, wave = tid >> 6;
  const int wr = wave >> 1, wc = wave & 1;          // 2x2 waves: 64(m) x 32(n) each
  const int r16 = lane & 15, kg = lane >> 4;

  // bijective XCD swizzle (1024 blocks % 8 == 0): chunk of 128 consecutive
  // flat ids per XCD -> A-panel reuse in per-XCD L2 (T1)
  const int flat = blockIdx.y * gridDim.x + blockIdx.x;
  const int swz = (flat & 7) * 128 + (flat >> 3);
  const int by = swz >> 5, bx = swz & 31;
  const int row0 = by * 128;                         // batch dim
  const int col0 = bx * 64;                          // output-feature dim

  f32x4 acc[4][2] = {};

  const int srow = tid >> 2;            // 0..63
  const int scol = (tid & 3) * 8;       // 0..31, 8-elem aligned

  for (int k0 = 0; k0 < kN; k0 += 32) {
    __syncthreads();                    // previous tile fully consumed
#pragma unroll
    for (int s = 0; s < 2; ++s)
      gload_lds16(A + (size_t)(row0 + s * 64 + srow) * kN + k0 + scol,
                  (char*)As + s * 4096 + wave * 1024);
    gload_lds16(Bt + (size_t)(col0 + srow) * kN + k0 + scol,
                (char*)Bs + wave * 1024);
    __syncthreads();                    // staging complete (vmcnt drained)

    short8 af[4], bf[2];
#pragma unroll
    for (int mt = 0; mt < 4; ++mt)
      af[mt] = *(const short8*)&As[wr * 64 + mt * 16 + r16][kg * 8];
#pragma unroll
    for (int nt = 0; nt < 2; ++nt)
      bf[nt] = *(const short8*)&Bs[wc * 32 + nt * 16 + r16][kg * 8];
#pragma unroll
    for (int mt = 0; mt < 4; ++mt)
#pragma unroll
      for (int nt = 0; nt < 2; ++nt)
        acc[mt][nt] = __builtin_amdgcn_mfma_f32_16x16x32_bf16(
            af[mt], bf[nt], acc[mt][nt], 0, 0, 0);
  }

  // epilogue: D row = (lane>>4)*4 + reg, col = lane&15 (verified layout)
#pragma unroll
  for (int mt = 0; mt < 4; ++mt)
#pragma unroll
    for (int nt = 0; nt < 2; ++nt) {
      const int r = row0 + wr * 64 + mt * 16 + kg * 4;
      const int c = col0 + wc * 32 + nt * 16 + r16;
#pragma unroll
      for (int j = 0; j < 4; ++j)
        C[(size_t)(r + j) * kN + c] = acc[mt][nt][j];
    }
}

extern "C" void kernel_launch(void* const* d_in, const int* in_sizes, int n_in,
                              void* d_out, int out_size, void* d_ws, size_t ws_size,
                              hipStream_t stream) {
  const float* x = (const float*)d_in[0];
  const float* G = (const float*)d_in[1];
  const float* H = (const float*)d_in[2];
  float* out = (float*)d_out;

  char* ws = (char*)d_ws;
  unsigned short* Mb = (unsigned short*)ws;                      // 8 MB  bf16 M[i][j]
  unsigned short* xb = (unsigned short*)(ws + (8u << 20));       // 16 MB bf16 x
  unsigned short* Dp = (unsigned short*)(ws + (24u << 20));      // 8 MB  bf16 diag-major

  const int cast_blocks = (kB * kN) / (256 * 8);                 // 4096
  prep_kernel<<<dim3(cast_blocks + kN), dim3(256), 0, stream>>>(x, G, H, xb, Dp);
  build_M_kernel<<<dim3(kN / 64, kN / 64), dim3(256), 0, stream>>>(Dp, Mb);
  gemm_kernel<<<dim3(kN / 64, kB / 128), dim3(256), 0, stream>>>(xb, Mb, out);
}

// Round 3
// 165.856 us; speedup vs baseline: 1.0837x; 1.0581x over previous
//
#include <hip/hip_runtime.h>
#include <cstdint>
#include <cstddef>

constexpr int kN = 2048;   // layer size (power of 2 -> cheap mod)
constexpr int kB = 4096;   // batch
constexpr int kR = 4;      // displacement rank

typedef __attribute__((ext_vector_type(4))) float f32x4;
typedef __attribute__((ext_vector_type(8))) short short8;
typedef __attribute__((ext_vector_type(8))) unsigned short ushort8;

__device__ __forceinline__ unsigned short f2bf(float f) {
  unsigned u = __float_as_uint(f);
  u += 0x7FFFu + ((u >> 16) & 1u);   // round-to-nearest-even
  return (unsigned short)(u >> 16);
}

__device__ __forceinline__ void gload_lds16(const void* g, void* l) {
  __builtin_amdgcn_global_load_lds(
      (const __attribute__((address_space(1))) void*)g,
      (__attribute__((address_space(3))) void*)l, 16, 0, 0);
}

// ---------------- kernel 1 (fused): cast x->bf16  +  per-diagonal prefix scan ----------------
__global__ void prep_kernel(const float* __restrict__ x,
                            const float* __restrict__ G,
                            const float* __restrict__ H,
                            unsigned short* __restrict__ xb,
                            unsigned short* __restrict__ Dp) {
  __shared__ float wsum[4];
  const int tid = threadIdx.x;

  if (blockIdx.x < (kB * kN) / (256 * 8)) {
    const int t = blockIdx.x * 256 + tid;
    const float4* xv = (const float4*)x;
    float4 a = xv[t * 2];
    float4 b = xv[t * 2 + 1];
    ushort8 o;
    o[0] = f2bf(a.x); o[1] = f2bf(a.y); o[2] = f2bf(a.z); o[3] = f2bf(a.w);
    o[4] = f2bf(b.x); o[5] = f2bf(b.y); o[6] = f2bf(b.z); o[7] = f2bf(b.w);
    *(ushort8*)(xb + (size_t)t * 8) = o;
    return;
  }

  const int d = blockIdx.x - (kB * kN) / (256 * 8);
  const int lane = tid & 63, wave = tid >> 6;
  const int v0 = tid * 8;

  float loc[8];
  float run = 0.f;
#pragma unroll
  for (int jj = 0; jj < 8; ++jj) {
    const int v = v0 + jj;
    float q = 0.f;
#pragma unroll
    for (int t = 0; t < kR; ++t)
      q += G[t * kN + ((v + d) & (kN - 1))] * H[t * kN + v];
    run += q;
    loc[jj] = run;                      // inclusive within thread
  }

  float incl = run;
#pragma unroll
  for (int off = 1; off < 64; off <<= 1) {
    float tv = __shfl_up(incl, off, 64);
    if (lane >= off) incl += tv;
  }
  if (lane == 63) wsum[wave] = incl;
  __syncthreads();
  float woff = 0.f, total = 0.f;
#pragma unroll
  for (int w = 0; w < 4; ++w) {
    const float s = wsum[w];
    total += s;
    if (w < wave) woff += s;
  }
  const float exc = woff + incl - run;  // exclusive prefix for this thread

  ushort8 o;
#pragma unroll
  for (int jj = 0; jj < 8; ++jj)
    o[jj] = f2bf(2.f * (exc + loc[jj]) - total);
  *(ushort8*)(Dp + (size_t)d * kN + v0) = o;
}

// ---------------- kernel 2: diagonal -> row-major transpose ----------------
__global__ void build_M_kernel(const unsigned short* __restrict__ Dp,
                               unsigned short* __restrict__ Mb) {
  __shared__ unsigned short lds[128][64];
  const int tid = threadIdx.x;
  const int i0 = blockIdx.y * 64, j0 = blockIdx.x * 64;
  const int delta0 = (i0 - j0 - 63) & (kN - 1);
#pragma unroll
  for (int it = 0; it < 32; ++it) {
    const int lin = it * 256 + tid;
    const int dd = lin >> 6, jj = lin & 63;
    lds[dd][jj] = Dp[(size_t)((delta0 + dd) & (kN - 1)) * kN + j0 + jj];
  }
  __syncthreads();
#pragma unroll
  for (int it = 0; it < 16; ++it) {
    const int lin = it * 256 + tid;
    const int ii = lin >> 6, jj = lin & 63;
    Mb[(size_t)(i0 + ii) * kN + j0 + jj] = lds[ii - jj + 63][jj];
  }
}

// ---------------- kernel 3: out = x @ M^T  (bf16 MFMA, min-2-phase double-buffer) ----------------
// BM=BN=128, BK=64, 4 waves (2x2), per-wave 64x64 -> 32 MFMA / K-tile / wave.
// T3-minimum: STAGE(next) issued BEFORE compute(cur); single __syncthreads()
// (= vmcnt(0)+lgkmcnt(0)+barrier) per K-tile -> loads overlap a full tile of compute.
// LDS layout per buffer: [slice s=k/32][row][32k], 16B-chunk XOR-swizzled with row&3;
// source pre-swizzled with the same involution (linear gload_lds dest, rule #21).
__global__ __launch_bounds__(256) void gemm_kernel(
    const unsigned short* __restrict__ A,
    const unsigned short* __restrict__ Bt,
    float* __restrict__ C) {
  __shared__ unsigned short As[2][8192];   // 2 x 16 KB
  __shared__ unsigned short Bs[2][8192];   // 2 x 16 KB  (total 64 KB -> 2 blocks/CU)

  const int tid = threadIdx.x;
  const int lane = tid & 63, wave = tid >> 6;
  const int wr = wave >> 1, wc = wave & 1;          // 2x2 waves, 64x64 each
  const int r16 = lane & 15, kg = lane >> 4;

  // T1 bijective XCD swizzle (512 blocks % 8 == 0)
  const int flat = blockIdx.y * gridDim.x + blockIdx.x;
  const int swz = (flat & 7) * 64 + (flat >> 3);
  const int by = swz >> 4, bx = swz & 15;
  const int row0 = by * 128, col0 = bx * 128;

  const unsigned short* Abase = A + (size_t)row0 * kN;
  const unsigned short* Bbase = Bt + (size_t)col0 * kN;
  const int ldsw = wave * 1024;            // wave-uniform LDS sub-base (bytes)

  f32x4 acc[4][4] = {};

  auto stage = [&](const unsigned short* src, unsigned short* dstbase) {
#pragma unroll
    for (int i = 0; i < 4; ++i) {
      const int r = (i & 1) * 64 + (tid >> 2);                     // row 0..127
      const int gbyte = r * (kN * 2) + (i >> 1) * 64               // k-slice
                        + (((tid & 3) ^ (r & 3)) * 16);            // pre-swizzled chunk
      gload_lds16((const char*)src + gbyte, (char*)dstbase + i * 4096 + ldsw);
    }
  };

  // prologue: stage tile 0 into buffer 0, drain
  stage(Abase, As[0]);
  stage(Bbase, Bs[0]);
  __syncthreads();

  for (int t = 0; t < kN / 64; ++t) {
    const int cur = t & 1;
    if (t < kN / 64 - 1) {                 // issue next tile's loads FIRST
      stage(Abase + (t + 1) * 64, As[cur ^ 1]);
      stage(Bbase + (t + 1) * 64, Bs[cur ^ 1]);
    }
    __builtin_amdgcn_sched_barrier(0);     // keep load-issue ahead of compute

    short8 af[2][4], bf[2][4];
#pragma unroll
    for (int s = 0; s < 2; ++s)
#pragma unroll
      for (int mt = 0; mt < 4; ++mt) {
        const int row = wr * 64 + mt * 16 + r16;
        af[s][mt] = *(const short8*)&As[cur][s * 4096 + row * 32 + ((kg ^ (row & 3)) << 3)];
      }
#pragma unroll
    for (int s = 0; s < 2; ++s)
#pragma unroll
      for (int nt = 0; nt < 4; ++nt) {
        const int row = wc * 64 + nt * 16 + r16;
        bf[s][nt] = *(const short8*)&Bs[cur][s * 4096 + row * 32 + ((kg ^ (row & 3)) << 3)];
      }
#pragma unroll
    for (int mt = 0; mt < 4; ++mt)
#pragma unroll
      for (int nt = 0; nt < 4; ++nt)
#pragma unroll
        for (int s = 0; s < 2; ++s)
          acc[mt][nt] = __builtin_amdgcn_mfma_f32_16x16x32_bf16(
              af[s][mt], bf[s][nt], acc[mt][nt], 0, 0, 0);

    __syncthreads();                       // vmcnt(0)+lgkmcnt(0)+barrier, once per K-tile
  }

  // epilogue: D row = (lane>>4)*4 + reg, col = lane&15 (verified layout)
#pragma unroll
  for (int mt = 0; mt < 4; ++mt)
#pragma unroll
    for (int nt = 0; nt < 4; ++nt) {
      const int r = row0 + wr * 64 + mt * 16 + kg * 4;
      const int c = col0 + wc * 64 + nt * 16 + r16;
#pragma unroll
      for (int j = 0; j < 4; ++j)
        C[(size_t)(r + j) * kN + c] = acc[mt][nt][j];
    }
}

extern "C" void kernel_launch(void* const* d_in, const int* in_sizes, int n_in,
                              void* d_out, int out_size, void* d_ws, size_t ws_size,
                              hipStream_t stream) {
  const float* x = (const float*)d_in[0];
  const float* G = (const float*)d_in[1];
  const float* H = (const float*)d_in[2];
  float* out = (float*)d_out;

  char* ws = (char*)d_ws;
  unsigned short* Mb = (unsigned short*)ws;                      // 8 MB  bf16 M[i][j]
  unsigned short* xb = (unsigned short*)(ws + (8u << 20));       // 16 MB bf16 x
  unsigned short* Dp = (unsigned short*)(ws + (24u << 20));      // 8 MB  bf16 diag-major

  const int cast_blocks = (kB * kN) / (256 * 8);                 // 4096
  prep_kernel<<<dim3(cast_blocks + kN), dim3(256), 0, stream>>>(x, G, H, xb, Dp);
  build_M_kernel<<<dim3(kN / 64, kN / 64), dim3(256), 0, stream>>>(Dp, Mb);
  gemm_kernel<<<dim3(kN / 128, kB / 128), dim3(256), 0, stream>>>(xb, Mb, out);
}